// Round 12
// baseline (86.043 us; speedup 1.0000x reference)
//
#include <hip/hip_runtime.h>
#include <hip/hip_bf16.h>

#define BATCH 2048
#define IDIM  256
#define ODIM  64
#define GRIDN 300

typedef __bf16 bf16x8 __attribute__((ext_vector_type(8)));
typedef float  f32x16 __attribute__((ext_vector_type(16)));
typedef float  f32x2  __attribute__((ext_vector_type(2)));
typedef unsigned int uint4v __attribute__((ext_vector_type(4)));

#define AS1 __attribute__((address_space(1)))
#define AS3 __attribute__((address_space(3)))

// Session rules: NO unions in hot paths (R4/R5/R6 scratch-demotion);
// NO launch_bounds below natural allocation (R8 spill); NO __float2bfloat16
// in hot loops (R9: ~5-inst software RNE); HW v_cvt_pk_bf16_f32 instead.
__device__ __forceinline__ unsigned short f2bf(float f) {   // cold paths only
    return __builtin_bit_cast(unsigned short, __float2bfloat16(f));
}

// ---------------------------------------------------------------------------
// Prep (unchanged — proven): fouriercoeffs [2][64][256][300] f32 -> WP bf16
// 4KB chunks, one per (isplit ib, g).
// In-chunk byte = q*1024 + j*16 + (il&3)*4 + t*2, q = il>>2.
// ---------------------------------------------------------------------------
__global__ __launch_bounds__(256) void fkan_prep(const float* __restrict__ fc,
                                                 char* __restrict__ wp) {
    __shared__ alignas(16) char lds[32768];
    const int blk = blockIdx.x;
    const int ib  = blk & 15;          // i-split 0..15
    const int gb  = blk >> 4;          // 0..37
    const int g0  = gb * 8;
    const int G   = (gb == 37) ? 4 : 8;   // 300 = 37*8 + 4
    const int q   = threadIdx.x >> 6;     // wave = il quad
    const int j   = threadIdx.x & 63;     // lane = output col

    float vals[2][4][8];
    #pragma unroll
    for (int t = 0; t < 2; ++t) {
        #pragma unroll
        for (int e = 0; e < 4; ++e) {
            const float* src = fc + (((size_t)t * ODIM + j) * IDIM
                                     + (ib * 16 + q * 4 + e)) * GRIDN + g0;
            float4 lo = *(const float4*)(src);
            vals[t][e][0] = lo.x; vals[t][e][1] = lo.y;
            vals[t][e][2] = lo.z; vals[t][e][3] = lo.w;
            if (G == 8) {
                float4 hi = *(const float4*)(src + 4);
                vals[t][e][4] = hi.x; vals[t][e][5] = hi.y;
                vals[t][e][6] = hi.z; vals[t][e][7] = hi.w;
            }
        }
    }
    #pragma unroll
    for (int g = 0; g < 8; ++g) {
        if (g < 4 || G == 8) {
            uint4v dw;
            #pragma unroll
            for (int e = 0; e < 4; ++e)
                dw[e] = (unsigned)f2bf(vals[0][e][g]) | ((unsigned)f2bf(vals[1][e][g]) << 16);
            *(uint4v*)(lds + g * 4096 + q * 1024 + j * 16) = dw;
        }
    }
    __syncthreads();
    char* dst = wp + ((size_t)ib * GRIDN + g0) * 4096;
    for (int w = threadIdx.x * 16; w < G * 4096; w += 256 * 16)
        *(uint4v*)(dst + w) = *(const uint4v*)(lds + w);
}

// ---------------------------------------------------------------------------
// Main — B-REUSE RESTRUCTURE. Evidence: R7==R9 (TLP-invariant), R10==R11
// (counted vmcnt neutral) -> dependency/issue-bound, not occupancy/barrier.
// So change the work ratio: B-frags depend only on (kgrp, jcol), NOT row ->
// a 64-row wave reuses its 4 ds_read_b128 for 8 MFMAs (was 4):
//   * LDS reads per CU halve (24us -> 12us pipe time)
//   * 4 independent acc chains (acc[rh][colh]) -> 2x MFMA ILP
// Block = 128 threads = 2 waves x (64 rows x 64 cols); grid 1024 unchanged
// (16 mtile x 16 isplit x 4 gq, XCD-swizzled), 4 blocks/CU, 8 waves/CU.
// Staging: R10's proven 2-buf __syncthreads (ring was neutral), 3-g/12KB
// stages = 6 DMA insts (128 thr x 16B = 2KB each). LDS 24KB x 4 = 96KB/CU.
// Per lane: 16 trig states (2 row-halves x 2 i-halves x 4), ~110 VGPR +
// 64 AGPR, natural allocation (no min-waves bound).
// ---------------------------------------------------------------------------
__global__ __launch_bounds__(128) void fkan_main(const float* __restrict__ x,
                                                 const char* __restrict__ wp,
                                                 float* __restrict__ out) {
    __shared__ alignas(16) char lds[2][12288];

    const int bid    = blockIdx.x;               // 0..1023
    const int xcd    = bid & 7;
    const int within = bid >> 3;                 // 0..127
    const int slice  = xcd * 8 + (within & 7);   // 0..63  (isplit x gq)
    const int mtile  = within >> 3;              // 0..15
    const int isplit = slice >> 2;               // 0..15
    const int gq     = slice & 3;                // 0..3
    const int g_begin = gq * 75;

    const int tid  = threadIdx.x;                // 0..127
    const int wave = tid >> 6;                   // 0..1
    const int lane = tid & 63;
    const int l31  = lane & 31;
    const int kgrp = lane >> 5;
    const int rowbase = mtile * 128 + wave * 64; // wave owns 64 rows

    // --- init 16 recurrence states: flat q = rh*4 + ih*2 + (p>>1), elem p&1
    //     i = isplit*16 + ih*8 + kgrp*4 + p ; row = rowbase + rh*32 + l31
    f32x2 vc[8], vs[8], vbc[8], vbs[8];
    #pragma unroll
    for (int rh = 0; rh < 2; ++rh) {
        const float* xrow = x + (size_t)(rowbase + rh * 32 + l31) * IDIM + isplit * 16;
        #pragma unroll
        for (int ih = 0; ih < 2; ++ih) {
            const float4 xv4 = *(const float4*)(xrow + ih * 8 + kgrp * 4);
            float xa[4] = {xv4.x, xv4.y, xv4.z, xv4.w};
            #pragma unroll
            for (int p = 0; p < 4; ++p) {
                const int q = rh * 4 + ih * 2 + (p >> 1);
                const float xv = xa[p];
                float sb, cb;
                __sincosf(xv, &sb, &cb);
                vbc[q][p & 1] = cb; vbs[q][p & 1] = sb;
                float s0 = sb, c0 = cb;
                if (g_begin != 0) __sincosf((float)(g_begin + 1) * xv, &s0, &c0);
                vc[q][p & 1] = c0; vs[q][p & 1] = s0;
            }
        }
    }

    // B-frag read base inside a 4KB g-slice: q*1024 + j*16, q = kc*2+kgrp
    const unsigned aq = (unsigned)kgrp * 1024 + (unsigned)l31 * 16;
    const char* wbase = wp + ((size_t)(isplit * GRIDN + g_begin)) * 4096 + tid * 16;

    // prologue: stage iter-0's 3 g-slices (12KB = 6 insts x 2KB) into buf 0
    #pragma unroll
    for (int p = 0; p < 6; ++p)
        __builtin_amdgcn_global_load_lds(
            (const AS1 unsigned int*)(wbase + (size_t)p * 2048),
            (AS3 unsigned int*)(&lds[0][0] + p * 2048 + tid * 16), 16, 0, 0);
    __syncthreads();

    f32x16 acc00 = {0,0,0,0,0,0,0,0,0,0,0,0,0,0,0,0};  // rh0 x cols 0..31
    f32x16 acc01 = {0,0,0,0,0,0,0,0,0,0,0,0,0,0,0,0};  // rh0 x cols 32..63
    f32x16 acc10 = {0,0,0,0,0,0,0,0,0,0,0,0,0,0,0,0};  // rh1 x cols 0..31
    f32x16 acc11 = {0,0,0,0,0,0,0,0,0,0,0,0,0,0,0,0};  // rh1 x cols 32..63

    for (int it = 0; it < 25; ++it) {
        const int cur = it & 1;
        // issue next 12KB stage; dest buffer's reads sealed by prev barrier
        if (it + 1 < 25) {
            #pragma unroll
            for (int p = 0; p < 6; ++p)
                __builtin_amdgcn_global_load_lds(
                    (const AS1 unsigned int*)(wbase + ((size_t)(it + 1) * 6 + p) * 2048),
                    (AS3 unsigned int*)(&lds[cur ^ 1][0] + p * 2048 + tid * 16),
                    16, 0, 0);
        }
        #pragma unroll
        for (int g = 0; g < 3; ++g) {
            const char* base = &lds[cur][0] + g * 4096;
            const bf16x8 b00 = *(const bf16x8*)(base + aq);           // kc0, cols 0..31
            const bf16x8 b01 = *(const bf16x8*)(base + aq + 512);     // kc0, cols 32..63
            const bf16x8 b10 = *(const bf16x8*)(base + aq + 2048);    // kc1, cols 0..31
            const bf16x8 b11 = *(const bf16x8*)(base + aq + 2560);    // kc1, cols 32..63
            // A-frags: af[rh][kc], dword p = bf16(cos)|bf16(sin)<<16 of state
            // q = rh*4 + kc*2 + (p>>1), elem p&1   (kc == ih)
            uint4v a00, a01, a10, a11;
            #pragma unroll
            for (int p = 0; p < 4; ++p) {
                unsigned r;
                asm("v_cvt_pk_bf16_f32 %0, %1, %2" : "=v"(r)
                    : "v"(vc[(p >> 1)][p & 1]),     "v"(vs[(p >> 1)][p & 1]));
                a00[p] = r;
                asm("v_cvt_pk_bf16_f32 %0, %1, %2" : "=v"(r)
                    : "v"(vc[2 + (p >> 1)][p & 1]), "v"(vs[2 + (p >> 1)][p & 1]));
                a01[p] = r;
                asm("v_cvt_pk_bf16_f32 %0, %1, %2" : "=v"(r)
                    : "v"(vc[4 + (p >> 1)][p & 1]), "v"(vs[4 + (p >> 1)][p & 1]));
                a10[p] = r;
                asm("v_cvt_pk_bf16_f32 %0, %1, %2" : "=v"(r)
                    : "v"(vc[6 + (p >> 1)][p & 1]), "v"(vs[6 + (p >> 1)][p & 1]));
                a11[p] = r;
            }
            const bf16x8 af00 = __builtin_bit_cast(bf16x8, a00);  // rh0 kc0
            const bf16x8 af01 = __builtin_bit_cast(bf16x8, a01);  // rh0 kc1
            const bf16x8 af10 = __builtin_bit_cast(bf16x8, a10);  // rh1 kc0
            const bf16x8 af11 = __builtin_bit_cast(bf16x8, a11);  // rh1 kc1
            __builtin_amdgcn_s_setprio(1);
            acc00 = __builtin_amdgcn_mfma_f32_32x32x16_bf16(af00, b00, acc00, 0, 0, 0);
            acc01 = __builtin_amdgcn_mfma_f32_32x32x16_bf16(af00, b01, acc01, 0, 0, 0);
            acc10 = __builtin_amdgcn_mfma_f32_32x32x16_bf16(af10, b00, acc10, 0, 0, 0);
            acc11 = __builtin_amdgcn_mfma_f32_32x32x16_bf16(af10, b01, acc11, 0, 0, 0);
            acc00 = __builtin_amdgcn_mfma_f32_32x32x16_bf16(af01, b10, acc00, 0, 0, 0);
            acc01 = __builtin_amdgcn_mfma_f32_32x32x16_bf16(af01, b11, acc01, 0, 0, 0);
            acc10 = __builtin_amdgcn_mfma_f32_32x32x16_bf16(af11, b10, acc10, 0, 0, 0);
            acc11 = __builtin_amdgcn_mfma_f32_32x32x16_bf16(af11, b11, acc11, 0, 0, 0);
            __builtin_amdgcn_s_setprio(0);
            // advance 16 states: v_pk_mul/v_pk_fma_f32
            #pragma unroll
            for (int q = 0; q < 8; ++q) {
                const f32x2 c = vc[q], s = vs[q];
                vc[q] = c * vbc[q] - s * vbs[q];
                vs[q] = s * vbc[q] + c * vbs[q];
            }
        }
        __syncthreads();   // drains vm+lgkm: next buf landed; this buf's reads sealed
    }

    // epilogue: D layout (32x32): col=lane&31, row=(r&3)+8*(r>>2)+4*(lane>>5)
    #pragma unroll
    for (int r = 0; r < 16; ++r) {
        const int rbase = (r & 3) + 8 * (r >> 2) + 4 * kgrp;
        const int orow0 = rowbase + rbase;
        const int orow1 = rowbase + 32 + rbase;
        unsafeAtomicAdd(out + (size_t)orow0 * ODIM + l31,      acc00[r]);
        unsafeAtomicAdd(out + (size_t)orow0 * ODIM + 32 + l31, acc01[r]);
        unsafeAtomicAdd(out + (size_t)orow1 * ODIM + l31,      acc10[r]);
        unsafeAtomicAdd(out + (size_t)orow1 * ODIM + 32 + l31, acc11[r]);
    }
}

// ---------------------------------------------------------------------------
// Fallback (ws too small): exact fp32, one thread per (b,j). Slow but correct.
// ---------------------------------------------------------------------------
__global__ __launch_bounds__(256) void fkan_naive(const float* __restrict__ x,
                                                  const float* __restrict__ fc,
                                                  float* __restrict__ out) {
    const int j = blockIdx.x >> 3;
    const int b = (blockIdx.x & 7) * 256 + threadIdx.x;
    const float* xr = x + (size_t)b * IDIM;
    float acc = 0.f;
    for (int i = 0; i < IDIM; ++i) {
        const float xv = xr[i];
        float sb, cb;
        __sincosf(xv, &sb, &cb);
        float c = cb, s = sb;
        const float* wc = fc + ((size_t)j * IDIM + i) * GRIDN;
        const float* ws = wc + (size_t)ODIM * IDIM * GRIDN;
        for (int g = 0; g < GRIDN; ++g) {
            acc += c * wc[g] + s * ws[g];
            const float cn = c * cb - s * sb;
            s = s * cb + c * sb;
            c = cn;
        }
    }
    out[(size_t)b * ODIM + j] = acc;
}

extern "C" void kernel_launch(void* const* d_in, const int* in_sizes, int n_in,
                              void* d_out, int out_size, void* d_ws, size_t ws_size,
                              hipStream_t stream) {
    const float* x  = (const float*)d_in[0];
    const float* fc = (const float*)d_in[1];
    float* out = (float*)d_out;
    constexpr size_t WPB = 16ull * GRIDN * 4096;   // 19.66 MB bf16 weight image

    if (ws_size >= WPB) {
        hipMemsetAsync(d_out, 0, (size_t)out_size * sizeof(float), stream);
        fkan_prep<<<608, 256, 0, stream>>>(fc, (char*)d_ws);
        fkan_main<<<1024, 128, 0, stream>>>(x, (const char*)d_ws, out);
    } else {
        fkan_naive<<<512, 256, 0, stream>>>(x, fc, out);
    }
}

// Round 13
// 82.680 us; speedup vs baseline: 1.0407x; 1.0407x over previous
//
#include <hip/hip_runtime.h>
#include <hip/hip_bf16.h>

#define BATCH 2048
#define IDIM  256
#define ODIM  64
#define GRIDN 300

typedef __bf16 bf16x8 __attribute__((ext_vector_type(8)));
typedef float  f32x16 __attribute__((ext_vector_type(16)));
typedef float  f32x2  __attribute__((ext_vector_type(2)));
typedef unsigned int uint4v __attribute__((ext_vector_type(4)));

#define AS1 __attribute__((address_space(1)))
#define AS3 __attribute__((address_space(3)))

// Session rules: NO unions in hot paths (R4/R5/R6 scratch-demotion);
// NO launch_bounds below natural allocation (R8 spill); NO __float2bfloat16
// in hot loops (R9: ~5-inst software RNE) -> HW v_cvt_pk_bf16_f32;
// f32x2 C-arithmetic may lower SCALAR (R10 VALUBusy ~2x pk estimate) ->
// force v_pk_mul/v_pk_fma via pure-VALU inline asm.
__device__ __forceinline__ unsigned short f2bf(float f) {   // cold paths only
    return __builtin_bit_cast(unsigned short, __float2bfloat16(f));
}

// ---------------------------------------------------------------------------
// Prep v3 — full-line reads. Old prep read 32B per 307KB-strided row -> half
// of every 64B line wasted (~78MB HBM vs 39MB ideal; ~18us). Now G=16 g's
// per block: each lane reads 64B (full line) per (t,e) row via 4x float4,
// all 64B consumed by the unrolled h-loop. Conversion via HW cvt_pk.
// Same proven chunk layout: chunk(ib,g) byte = q*1024 + j*16 + e*4 + t*2.
// Block = (ib, gb16): 16 x 19 = 304 blocks; LDS 16x4KB = 64KB; write-out
// fully coalesced (G*4KB linear stream).
// ---------------------------------------------------------------------------
__global__ __launch_bounds__(256) void fkan_prep(const float* __restrict__ fc,
                                                 char* __restrict__ wp) {
    __shared__ alignas(16) char lds[16][4096];
    const int blk = blockIdx.x;          // 0..303
    const int ib  = blk & 15;            // i-split
    const int gb  = blk >> 4;            // 0..18
    const int g0  = gb * 16;
    const int G   = (gb == 18) ? 12 : 16;   // 300 = 18*16 + 12
    const int q   = threadIdx.x >> 6;    // i-quad 0..3
    const int j   = threadIdx.x & 63;    // output col

    uint4v dw[16];                       // dw[g] = {e0,e1,e2,e3} dwords
    #pragma unroll
    for (int e = 0; e < 4; ++e) {
        const float* c_src = fc + ((size_t)j * IDIM + (ib * 16 + q * 4 + e)) * GRIDN + g0;
        const float* s_src = c_src + (size_t)ODIM * IDIM * GRIDN;
        float4 c4[4], s4[4];
        #pragma unroll
        for (int h = 0; h < 4; ++h) {
            if (h * 4 < G) {             // full 64B line consumed when G=16
                c4[h] = *(const float4*)(c_src + h * 4);
                s4[h] = *(const float4*)(s_src + h * 4);
            }
        }
        #pragma unroll
        for (int h = 0; h < 4; ++h) {
            float ca[4] = {c4[h].x, c4[h].y, c4[h].z, c4[h].w};
            float sa[4] = {s4[h].x, s4[h].y, s4[h].z, s4[h].w};
            #pragma unroll
            for (int d = 0; d < 4; ++d) {
                unsigned r;
                asm("v_cvt_pk_bf16_f32 %0, %1, %2" : "=v"(r) : "v"(ca[d]), "v"(sa[d]));
                dw[h * 4 + d][e] = r;
            }
        }
    }
    #pragma unroll
    for (int g = 0; g < 16; ++g)
        if (g < G)
            *(uint4v*)(&lds[g][0] + q * 1024 + j * 16) = dw[g];
    __syncthreads();
    char* dst = wp + ((size_t)ib * GRIDN + g0) * 4096;
    for (int w = threadIdx.x * 16; w < G * 4096; w += 256 * 16)
        *(uint4v*)(dst + w) = *(const uint4v*)(&lds[0][0] + w);
}

// ---------------------------------------------------------------------------
// Main — R10's best structure (56us: 2-buf __syncthreads, 3-g/12KB stages,
// 25 iters, 4 blocks/CU, HW cvt_pk A-frags, zero spill), ONE change:
// recurrence forced to v_pk_mul_f32 / v_pk_fma_f32 via inline asm
// (R10 VALUBusy 37% is ~2x the pk-instruction estimate -> compiler was
// lowering f32x2 ops scalar). vnbs = -vbs precomputed so no neg modifiers.
// vc' = c*bc + s*(-bs);  vs' = s*bc + c*bs   -> 4 pk insts per qq.
// ---------------------------------------------------------------------------
__global__ __launch_bounds__(256, 4) void fkan_main(const float* __restrict__ x,
                                                    const char* __restrict__ wp,
                                                    float* __restrict__ out) {
    __shared__ alignas(16) char lds[2][12288];

    const int bid    = blockIdx.x;               // 0..1023
    const int xcd    = bid & 7;
    const int within = bid >> 3;                 // 0..127
    const int slice  = xcd * 8 + (within & 7);   // 0..63  (isplit x gq)
    const int mtile  = within >> 3;              // 0..15
    const int isplit = slice >> 2;               // 0..15
    const int gq     = slice & 3;                // 0..3
    const int g_begin = gq * 75;

    const int tid  = threadIdx.x;
    const int wave = tid >> 6;
    const int lane = tid & 63;
    const int l31  = lane & 31;
    const int kgrp = lane >> 5;
    const int row  = mtile * 128 + wave * 32 + l31;   // batch row (A lane row)

    // --- init 8 recurrence states, packed f32x2; vnbs = -vbs ---
    f32x2 vc[4], vs[4], vbc[4], vbs[4], vnbs[4];
    const float* xrow = x + (size_t)row * IDIM + isplit * 16;
    #pragma unroll
    for (int h = 0; h < 2; ++h) {
        const float4 xv4 = *(const float4*)(xrow + h * 8 + kgrp * 4);
        float xa[4] = {xv4.x, xv4.y, xv4.z, xv4.w};
        #pragma unroll
        for (int p = 0; p < 4; ++p) {
            const int ss = h * 4 + p;
            const float xv = xa[p];
            float sb, cb;
            __sincosf(xv, &sb, &cb);
            vbc[ss >> 1][ss & 1] = cb; vbs[ss >> 1][ss & 1] = sb;
            vnbs[ss >> 1][ss & 1] = -sb;
            float s0 = sb, c0 = cb;
            if (g_begin != 0) __sincosf((float)(g_begin + 1) * xv, &s0, &c0);
            vc[ss >> 1][ss & 1] = c0; vs[ss >> 1][ss & 1] = s0;
        }
    }

    // B-frag read base inside a 4KB g-slice: q*1024 + j*16, q = kchunk*2+kgrp
    const unsigned aq = (unsigned)kgrp * 1024 + (unsigned)l31 * 16;
    const char* wbase = wp + ((size_t)(isplit * GRIDN + g_begin)) * 4096 + tid * 16;

    // prologue: stage iter-0's 3 g-slices (12KB) into buf 0
    #pragma unroll
    for (int p = 0; p < 3; ++p)
        __builtin_amdgcn_global_load_lds(
            (const AS1 unsigned int*)(wbase + (size_t)p * 4096),
            (AS3 unsigned int*)(&lds[0][0] + p * 4096 + tid * 16), 16, 0, 0);
    __syncthreads();

    f32x16 acc0 = {0,0,0,0,0,0,0,0,0,0,0,0,0,0,0,0};
    f32x16 acc1 = {0,0,0,0,0,0,0,0,0,0,0,0,0,0,0,0};

    for (int it = 0; it < 25; ++it) {
        const int cur = it & 1;
        // issue next 12KB stage; dest buffer's reads sealed by prev barrier
        if (it + 1 < 25) {
            #pragma unroll
            for (int p = 0; p < 3; ++p)
                __builtin_amdgcn_global_load_lds(
                    (const AS1 unsigned int*)(wbase + ((size_t)(it + 1) * 3 + p) * 4096),
                    (AS3 unsigned int*)(&lds[cur ^ 1][0] + p * 4096 + tid * 16),
                    16, 0, 0);
        }
        #pragma unroll
        for (int g = 0; g < 3; ++g) {
            const char* base = &lds[cur][0] + g * 4096;
            const bf16x8 b00 = *(const bf16x8*)(base + aq);           // kc0, cols 0..31
            const bf16x8 b01 = *(const bf16x8*)(base + aq + 512);     // kc0, cols 32..63
            const bf16x8 b10 = *(const bf16x8*)(base + aq + 2048);    // kc1, cols 0..31
            const bf16x8 b11 = *(const bf16x8*)(base + aq + 2560);    // kc1, cols 32..63
            // A-frags: HW packed convert. dword p = bf16(cos_p) | bf16(sin_p)<<16
            uint4v a1, a2;
            #pragma unroll
            for (int p = 0; p < 4; ++p) {
                const float c1f = vc[p >> 1][p & 1],       s1f = vs[p >> 1][p & 1];
                const float c2f = vc[2 + (p >> 1)][p & 1], s2f = vs[2 + (p >> 1)][p & 1];
                unsigned r1, r2;
                asm("v_cvt_pk_bf16_f32 %0, %1, %2" : "=v"(r1) : "v"(c1f), "v"(s1f));
                asm("v_cvt_pk_bf16_f32 %0, %1, %2" : "=v"(r2) : "v"(c2f), "v"(s2f));
                a1[p] = r1; a2[p] = r2;
            }
            const bf16x8 af1 = __builtin_bit_cast(bf16x8, a1);
            const bf16x8 af2 = __builtin_bit_cast(bf16x8, a2);
            __builtin_amdgcn_s_setprio(1);
            acc0 = __builtin_amdgcn_mfma_f32_32x32x16_bf16(af1, b00, acc0, 0, 0, 0);
            acc1 = __builtin_amdgcn_mfma_f32_32x32x16_bf16(af1, b01, acc1, 0, 0, 0);
            acc0 = __builtin_amdgcn_mfma_f32_32x32x16_bf16(af2, b10, acc0, 0, 0, 0);
            acc1 = __builtin_amdgcn_mfma_f32_32x32x16_bf16(af2, b11, acc1, 0, 0, 0);
            __builtin_amdgcn_s_setprio(0);
            // advance phases: FORCED packed math (4 pk insts per qq)
            #pragma unroll
            for (int qq = 0; qq < 4; ++qq) {
                f32x2 t, u, cn, sn;
                asm("v_pk_mul_f32 %0, %1, %2" : "=v"(t) : "v"(vs[qq]), "v"(vnbs[qq]));
                asm("v_pk_mul_f32 %0, %1, %2" : "=v"(u) : "v"(vc[qq]), "v"(vbs[qq]));
                asm("v_pk_fma_f32 %0, %1, %2, %3" : "=v"(cn) : "v"(vc[qq]), "v"(vbc[qq]), "v"(t));
                asm("v_pk_fma_f32 %0, %1, %2, %3" : "=v"(sn) : "v"(vs[qq]), "v"(vbc[qq]), "v"(u));
                vc[qq] = cn; vs[qq] = sn;
            }
        }
        __syncthreads();   // drains vm+lgkm: next buf landed; this buf's reads sealed
    }

    // epilogue: D layout (32x32): col=lane&31, row=(r&3)+8*(r>>2)+4*(lane>>5)
    #pragma unroll
    for (int r = 0; r < 16; ++r) {
        const int orow = mtile * 128 + wave * 32 + (r & 3) + 8 * (r >> 2) + 4 * kgrp;
        unsafeAtomicAdd(out + (size_t)orow * ODIM + l31, acc0[r]);
        unsafeAtomicAdd(out + (size_t)orow * ODIM + 32 + l31, acc1[r]);
    }
}

// ---------------------------------------------------------------------------
// Fallback (ws too small): exact fp32, one thread per (b,j). Slow but correct.
// ---------------------------------------------------------------------------
__global__ __launch_bounds__(256) void fkan_naive(const float* __restrict__ x,
                                                  const float* __restrict__ fc,
                                                  float* __restrict__ out) {
    const int j = blockIdx.x >> 3;
    const int b = (blockIdx.x & 7) * 256 + threadIdx.x;
    const float* xr = x + (size_t)b * IDIM;
    float acc = 0.f;
    for (int i = 0; i < IDIM; ++i) {
        const float xv = xr[i];
        float sb, cb;
        __sincosf(xv, &sb, &cb);
        float c = cb, s = sb;
        const float* wc = fc + ((size_t)j * IDIM + i) * GRIDN;
        const float* ws = wc + (size_t)ODIM * IDIM * GRIDN;
        for (int g = 0; g < GRIDN; ++g) {
            acc += c * wc[g] + s * ws[g];
            const float cn = c * cb - s * sb;
            s = s * cb + c * sb;
            c = cn;
        }
    }
    out[(size_t)b * ODIM + j] = acc;
}

extern "C" void kernel_launch(void* const* d_in, const int* in_sizes, int n_in,
                              void* d_out, int out_size, void* d_ws, size_t ws_size,
                              hipStream_t stream) {
    const float* x  = (const float*)d_in[0];
    const float* fc = (const float*)d_in[1];
    float* out = (float*)d_out;
    constexpr size_t WPB = 16ull * GRIDN * 4096;   // 19.66 MB bf16 weight image

    if (ws_size >= WPB) {
        hipMemsetAsync(d_out, 0, (size_t)out_size * sizeof(float), stream);
        fkan_prep<<<304, 256, 0, stream>>>(fc, (char*)d_ws);
        fkan_main<<<1024, 256, 0, stream>>>(x, (const char*)d_ws, out);
    } else {
        fkan_naive<<<512, 256, 0, stream>>>(x, fc, out);
    }
}